// Round 2
// baseline (580.746 us; speedup 1.0000x reference)
//
#include <hip/hip_runtime.h>
#include <hip/hip_bf16.h>
#include <stdint.h>

#define NROWS 262144

typedef __bf16 bf16x8 __attribute__((ext_vector_type(8)));
typedef float f32x4 __attribute__((ext_vector_type(4)));

#define MFMA(a,b,c) __builtin_amdgcn_mfma_f32_16x16x32_bf16(a,b,c,0,0,0)

// ws images (byte-exact LDS images, staged linearly)
#define WS_W0 0          // 16KB: [plane][g:4][n:128] cells of 8 bf16 (k = g*8+j)
#define WS_W1 16384      // 64KB: 4 rounds kr, each [plane][q:4][n:128] (k = kr*32+q*8+j)
#define WS_WP 81920      // 512KB: 32 chunks d, each [plane][g:16][n:32] (k = g*8+j, col = d*32+n)
#define WS_BP 606208     // 4KB: bp padded 25->32 per dim

// LDS regions (4 x 16KB = 64KB)
#define R1 0             // W0 -> h1/h2 transpose scratch (wave stripes) -> raw dbuf 2x8KB
#define R2 16384         // xmA hi/lo (8KB) -> W1 kr1/kr3 -> even chunks
#define R3 32768         // W1 kr0/kr2 -> odd chunks
#define R4 49152         // xu [32][64] f32 (8KB) + yu [32][64] f32 (8KB)

__device__ __forceinline__ unsigned short f2bf(float f){
    unsigned int u = __float_as_uint(f);
    u = (u + 0x7FFFu + ((u >> 16) & 1u)) >> 16;
    return (unsigned short)u;
}
__device__ __forceinline__ float bf2f(unsigned short h){
    return __uint_as_float(((unsigned int)h) << 16);
}

__global__ __launch_bounds__(256) void prep_kernel(
    const float* __restrict__ W0, const float* __restrict__ W1,
    const float* __restrict__ Wp, const float* __restrict__ bp,
    char* __restrict__ ws)
{
    int tid = blockIdx.x * 256 + threadIdx.x;   // grid 152 -> 38912 threads
    if (tid < 32768){                            // Wp chunks
        int d = tid >> 10, r = tid & 1023;
        int plane = r >> 9, g = (r >> 5) & 15, n = r & 31;
        unsigned short cell[8];
        #pragma unroll
        for (int j = 0; j < 8; j++){
            int k = g*8 + j;
            float v = (n < 25) ? Wp[k*800 + d*25 + n] : 0.f;
            unsigned short hi = f2bf(v);
            cell[j] = plane ? f2bf(v - bf2f(hi)) : hi;
        }
        *(uint4*)(ws + WS_WP + d*16384 + plane*8192 + (g*32+n)*16) = *(uint4*)cell;
    } else if (tid < 36864){                     // W1 rounds
        int i = tid - 32768;
        int kr = i >> 10, r = i & 1023;
        int plane = r >> 9, q = (r >> 7) & 3, n = r & 127;
        unsigned short cell[8];
        #pragma unroll
        for (int j = 0; j < 8; j++){
            int k = kr*32 + q*8 + j;
            float v = W1[k*128 + n];
            unsigned short hi = f2bf(v);
            cell[j] = plane ? f2bf(v - bf2f(hi)) : hi;
        }
        *(uint4*)(ws + WS_W1 + kr*16384 + plane*8192 + (q*128+n)*16) = *(uint4*)cell;
    } else if (tid < 37888){                     // W0
        int i = tid - 36864;
        int plane = i >> 9, g = (i >> 7) & 3, n = i & 127;
        unsigned short cell[8];
        #pragma unroll
        for (int j = 0; j < 8; j++){
            int k = g*8 + j;
            float v = W0[k*128 + n];
            unsigned short hi = f2bf(v);
            cell[j] = plane ? f2bf(v - bf2f(hi)) : hi;
        }
        *(uint4*)(ws + WS_W0 + plane*8192 + (g*128+n)*16) = *(uint4*)cell;
    } else if (tid < 38912){                     // bp padded
        int i = tid - 37888;
        int d = i >> 5, n = i & 31;
        ((float*)(ws + WS_BP))[i] = (n < 25) ? bp[d*25 + n] : 0.f;
    }
}

__global__ __launch_bounds__(256, 2) void main_kernel(
    const float* __restrict__ x,
    const float* __restrict__ pb0, const float* __restrict__ pg0, const float* __restrict__ pbe0,
    const float* __restrict__ pb1, const float* __restrict__ pg1, const float* __restrict__ pbe1,
    const char* __restrict__ ws,
    float* __restrict__ yout, float* __restrict__ ldout)
{
    __shared__ __align__(16) char smem[65536];
    const int t = threadIdx.x;
    const int r0 = blockIdx.x * 64;
    const int w = t >> 6, lane = t & 63, l16 = lane & 15, q = lane >> 4;
    const float* bpp = (const float*)(ws + WS_BP);
    const f32x4 fzero = {0.f, 0.f, 0.f, 0.f};

    auto stage16k = [&](int dstoff, int srcoff){
        #pragma unroll
        for (int k = 0; k < 4; k++){
            int cell = t + 256*k;
            ((uint4*)(smem + dstoff))[cell] = ((const uint4*)(ws + srcoff))[cell];
        }
    };

    // ---------------- phase 0: x -> xmA(hi/lo) + xu ; stage W0, W1 kr0 ----------------
    #pragma unroll
    for (int k = 0; k < 4; k++){
        int i = t + 256*k;                 // 1024 float4s of the 64x64 x tile
        int row = i >> 4, s = i & 15;
        float4 v = ((const float4*)(x + (size_t)(r0 + row) * 64))[s];
        unsigned short h0 = f2bf(v.x), h1s = f2bf(v.z);
        unsigned short l0 = f2bf(v.x - bf2f(h0)), l1 = f2bf(v.z - bf2f(h1s));
        int g = s >> 2, ofs = (s & 3) * 4;
        *(unsigned int*)(smem + R2 + (g*64 + row)*16 + ofs) = (unsigned int)h0 | ((unsigned int)h1s << 16);
        *(unsigned int*)(smem + R2 + 4096 + (g*64 + row)*16 + ofs) = (unsigned int)l0 | ((unsigned int)l1 << 16);
        *(float*)(smem + R4 + ((2*s)*64 + row)*4) = v.y;      // xu transposed [dim][row]
        *(float*)(smem + R4 + ((2*s+1)*64 + row)*4) = v.w;
    }
    stage16k(R1, WS_W0);
    stage16k(R3, WS_W1);                   // W1 kr0
    __syncthreads();

    // ---------------- phase 1: GEMM0 (split bf16x3) + LN0 + relu ----------------
    float h1r[8][4];
    {
        bf16x8 a_h = *(const bf16x8*)(smem + R2 + (q*64 + 16*w + l16)*16);
        bf16x8 a_l = *(const bf16x8*)(smem + R2 + 4096 + (q*64 + 16*w + l16)*16);
        f32x4 c0[8];
        #pragma unroll
        for (int nt = 0; nt < 8; nt++){
            int n = nt*16 + l16;
            bf16x8 b_h = *(const bf16x8*)(smem + R1 + (q*128 + n)*16);
            bf16x8 b_l = *(const bf16x8*)(smem + R1 + 8192 + (q*128 + n)*16);
            f32x4 acc = fzero;
            acc = MFMA(a_h, b_l, acc);
            acc = MFMA(a_l, b_h, acc);
            acc = MFMA(a_h, b_h, acc);
            c0[nt] = acc;
        }
        float s1[4] = {0,0,0,0}, s2[4] = {0,0,0,0};
        #pragma unroll
        for (int nt = 0; nt < 8; nt++){
            float bv = pb0[nt*16 + l16];
            #pragma unroll
            for (int rg = 0; rg < 4; rg++){
                float v = c0[nt][rg] + bv;
                c0[nt][rg] = v; s1[rg] += v; s2[rg] += v*v;
            }
        }
        #pragma unroll
        for (int m = 1; m < 16; m <<= 1)
            #pragma unroll
            for (int rg = 0; rg < 4; rg++){
                s1[rg] += __shfl_xor(s1[rg], m, 64);
                s2[rg] += __shfl_xor(s2[rg], m, 64);
            }
        #pragma unroll
        for (int rg = 0; rg < 4; rg++){
            float mean = s1[rg] * 0.0078125f;
            float var  = s2[rg] * 0.0078125f - mean*mean;
            s1[rg] = mean; s2[rg] = rsqrtf(var + 1e-6f);
        }
        #pragma unroll
        for (int nt = 0; nt < 8; nt++){
            float gv = pg0[nt*16 + l16], bev = pbe0[nt*16 + l16];
            #pragma unroll
            for (int rg = 0; rg < 4; rg++){
                float hv = (c0[nt][rg] - s1[rg]) * s2[rg] * gv + bev;
                h1r[nt][rg] = fmaxf(hv, 0.f);
            }
        }
    }
    __syncthreads();   // R1 (W0) and R2 (xmA) now free

    // stage W1 kr1 into R2; wave-local transpose of h1 -> A-frag registers (no barriers)
    stage16k(R2, WS_W1 + 16384);
    bf16x8 ah1[4], al1[4];
    {
        char* sb = smem + R1 + w*4096;     // wave stripe: [g:16][row:16] cells
        #pragma unroll
        for (int nt = 0; nt < 8; nt++){
            int col = nt*16 + l16;
            #pragma unroll
            for (int rg = 0; rg < 4; rg++)
                *(unsigned short*)(sb + ((col>>3)*16 + q*4+rg)*16 + (col&7)*2) = f2bf(h1r[nt][rg]);
        }
        #pragma unroll
        for (int kr = 0; kr < 4; kr++)
            ah1[kr] = *(const bf16x8*)(sb + ((kr*4+q)*16 + l16)*16);
        #pragma unroll
        for (int nt = 0; nt < 8; nt++){
            int col = nt*16 + l16;
            #pragma unroll
            for (int rg = 0; rg < 4; rg++){
                unsigned short hi = f2bf(h1r[nt][rg]);
                *(unsigned short*)(sb + ((col>>3)*16 + q*4+rg)*16 + (col&7)*2) = f2bf(h1r[nt][rg] - bf2f(hi));
            }
        }
        #pragma unroll
        for (int kr = 0; kr < 4; kr++)
            al1[kr] = *(const bf16x8*)(sb + ((kr*4+q)*16 + l16)*16);
    }

    // ---------------- phase 2: GEMM1 (4 K-rounds, split bf16x3) ----------------
    f32x4 c1[8];
    #pragma unroll
    for (int nt = 0; nt < 8; nt++) c1[nt] = fzero;
    auto g1round = [&](int base, bf16x8 ah, bf16x8 al){
        #pragma unroll
        for (int nt = 0; nt < 8; nt++){
            int n = nt*16 + l16;
            bf16x8 bh = *(const bf16x8*)(smem + base + (q*128 + n)*16);
            bf16x8 bl = *(const bf16x8*)(smem + base + 8192 + (q*128 + n)*16);
            c1[nt] = MFMA(ah, bl, c1[nt]);
            c1[nt] = MFMA(al, bh, c1[nt]);
            c1[nt] = MFMA(ah, bh, c1[nt]);
        }
    };
    g1round(R3, ah1[0], al1[0]);
    __syncthreads();
    stage16k(R3, WS_W1 + 32768);           // kr2
    g1round(R2, ah1[1], al1[1]);
    __syncthreads();
    stage16k(R2, WS_W1 + 49152);           // kr3
    g1round(R3, ah1[2], al1[2]);
    __syncthreads();
    g1round(R2, ah1[3], al1[3]);

    // LN1 + relu + residual -> h2 (into h1r)
    {
        float s1[4] = {0,0,0,0}, s2[4] = {0,0,0,0};
        #pragma unroll
        for (int nt = 0; nt < 8; nt++){
            float bv = pb1[nt*16 + l16];
            #pragma unroll
            for (int rg = 0; rg < 4; rg++){
                float v = c1[nt][rg] + bv;
                c1[nt][rg] = v; s1[rg] += v; s2[rg] += v*v;
            }
        }
        #pragma unroll
        for (int m = 1; m < 16; m <<= 1)
            #pragma unroll
            for (int rg = 0; rg < 4; rg++){
                s1[rg] += __shfl_xor(s1[rg], m, 64);
                s2[rg] += __shfl_xor(s2[rg], m, 64);
            }
        #pragma unroll
        for (int rg = 0; rg < 4; rg++){
            float mean = s1[rg] * 0.0078125f;
            float var  = s2[rg] * 0.0078125f - mean*mean;
            s1[rg] = mean; s2[rg] = rsqrtf(var + 1e-6f);
        }
        #pragma unroll
        for (int nt = 0; nt < 8; nt++){
            float gv = pg1[nt*16 + l16], bev = pbe1[nt*16 + l16];
            #pragma unroll
            for (int rg = 0; rg < 4; rg++){
                float hv = (c1[nt][rg] - s1[rg]) * s2[rg] * gv + bev;
                h1r[nt][rg] = fmaxf(hv, 0.f) + h1r[nt][rg];
            }
        }
    }
    __syncthreads();   // all waves done with R2/R3 weight reads

    // h2 -> A-frag registers (wave-local, R1); stage chunks 0/1
    bf16x8 ah2[4], al2[4];
    {
        char* sb = smem + R1 + w*4096;
        #pragma unroll
        for (int nt = 0; nt < 8; nt++){
            int col = nt*16 + l16;
            #pragma unroll
            for (int rg = 0; rg < 4; rg++)
                *(unsigned short*)(sb + ((col>>3)*16 + q*4+rg)*16 + (col&7)*2) = f2bf(h1r[nt][rg]);
        }
        #pragma unroll
        for (int kr = 0; kr < 4; kr++)
            ah2[kr] = *(const bf16x8*)(sb + ((kr*4+q)*16 + l16)*16);
        #pragma unroll
        for (int nt = 0; nt < 8; nt++){
            int col = nt*16 + l16;
            #pragma unroll
            for (int rg = 0; rg < 4; rg++){
                unsigned short hi = f2bf(h1r[nt][rg]);
                *(unsigned short*)(sb + ((col>>3)*16 + q*4+rg)*16 + (col&7)*2) = f2bf(h1r[nt][rg] - bf2f(hi));
            }
        }
        #pragma unroll
        for (int kr = 0; kr < 4; kr++)
            al2[kr] = *(const bf16x8*)(sb + ((kr*4+q)*16 + l16)*16);
    }
    stage16k(R2, WS_WP);                   // chunk 0
    stage16k(R3, WS_WP + 16384);           // chunk 1
    __syncthreads();

    // ---------------- phase 3: 32 chunks (1 dim each) ----------------
    float ld_acc = 0.f;
    for (int c = 0; c < 32; c++){
        const char* cb = smem + ((c & 1) ? R3 : R2);
        float bpv0 = bpp[c*32 + l16];
        float bpv1 = bpp[c*32 + 16 + l16];
        f32x4 c2a = fzero, c2b = fzero;
        #pragma unroll
        for (int kb = 0; kb < 4; kb++){
            bf16x8 bh0 = *(const bf16x8*)(cb + ((kb*4+q)*32 + l16)*16);
            bf16x8 bl0 = *(const bf16x8*)(cb + 8192 + ((kb*4+q)*32 + l16)*16);
            bf16x8 bh1 = *(const bf16x8*)(cb + ((kb*4+q)*32 + 16 + l16)*16);
            bf16x8 bl1 = *(const bf16x8*)(cb + 8192 + ((kb*4+q)*32 + 16 + l16)*16);
            c2a = MFMA(ah2[kb], bl0, c2a); c2a = MFMA(al2[kb], bh0, c2a); c2a = MFMA(ah2[kb], bh0, c2a);
            c2b = MFMA(ah2[kb], bl1, c2b); c2b = MFMA(al2[kb], bh1, c2b); c2b = MFMA(ah2[kb], bh1, c2b);
        }
        {   // raw write: [row][8 groups x 16B], group swizzle g^(row&7)
            char* rb = smem + R1 + (c & 1)*8192;
            #pragma unroll
            for (int rg = 0; rg < 4; rg++){
                int row = 16*w + q*4 + rg;
                int p0 = l16, p1 = 16 + l16;
                *(float*)(rb + row*128 + ((p0>>2) ^ (row&7))*16 + (p0&3)*4) = c2a[rg] + bpv0;
                *(float*)(rb + row*128 + ((p1>>2) ^ (row&7))*16 + (p1&3)*4) = c2b[rg] + bpv1;
            }
        }
        __syncthreads();
        int sw = c & 3;
        if (w != sw){
            if (c < 30){   // stage chunk c+2 into region (c&1), 3 waves share
                int wi = w - sw - 1; if (wi < 0) wi += 4;
                int tt = wi*64 + lane;
                int dstoff = (c & 1) ? R3 : R2;
                int srcoff = WS_WP + (c+2)*16384;
                for (int cell = tt; cell < 1024; cell += 192)
                    ((uint4*)(smem + dstoff))[cell] = ((const uint4*)(ws + srcoff))[cell];
            }
        } else {
            // spline for dim c, row = lane
            const char* rb = smem + R1 + (c & 1)*8192;
            float r[28];
            #pragma unroll
            for (int j = 0; j < 7; j++){
                float4 v4 = *(const float4*)(rb + lane*128 + ((j ^ (lane & 7))*16));
                r[4*j+0] = v4.x; r[4*j+1] = v4.y; r[4*j+2] = v4.z; r[4*j+3] = v4.w;
            }
            float mw = r[0];
            #pragma unroll
            for (int k = 1; k < 8; k++) mw = fmaxf(mw, r[k]);
            float ew[8], sm = 0.f;
            #pragma unroll
            for (int k = 0; k < 8; k++){ ew[k] = __expf(r[k] - mw); sm += ew[k]; }
            float inv = 1.f / sm;
            float wv[8];
            #pragma unroll
            for (int k = 0; k < 8; k++) wv[k] = 0.006f + 5.952f * ew[k] * inv;
            mw = r[8];
            #pragma unroll
            for (int k = 1; k < 8; k++) mw = fmaxf(mw, r[8+k]);
            sm = 0.f;
            #pragma unroll
            for (int k = 0; k < 8; k++){ ew[k] = __expf(r[8+k] - mw); sm += ew[k]; }
            inv = 1.f / sm;
            float hv[8];
            #pragma unroll
            for (int k = 0; k < 8; k++) hv[k] = 0.006f + 5.952f * ew[k] * inv;

            float xu = *(const float*)(smem + R4 + (c*64 + lane)*4);
            bool inside = (xu > -3.f) && (xu < 3.f);
            float xc = fminf(fmaxf(xu, -3.f), 3.f);
            float cwk = -3.f + wv[0], chk = -3.f + hv[0];
            float x_k = -3.f, y_k = -3.f, w_k = wv[0], h_k = hv[0];
            int idx = 0;
            #pragma unroll
            for (int k = 1; k < 8; k++){
                if (xc >= cwk){ x_k = cwk; y_k = chk; w_k = wv[k]; h_k = hv[k]; idx = k; }
                cwk += wv[k]; chk += hv[k];
            }
            float dkr = r[16], dk1r = r[17];
            #pragma unroll
            for (int k = 1; k < 8; k++)
                if (idx == k){ dkr = r[16+k]; dk1r = r[17+k]; }
            float d_k  = fmaxf(dkr, 0.f)  + __logf(1.f + __expf(-fabsf(dkr)))  + 0.001f;
            float d_k1 = fmaxf(dk1r, 0.f) + __logf(1.f + __expf(-fabsf(dk1r))) + 0.001f;
            float iw = 1.f / w_k;
            float s_ = h_k * iw;
            float th = (xc - x_k) * iw;
            float om = 1.f - th;
            float t1m = th * om;
            float den = s_ + (d_k1 + d_k - 2.f*s_) * t1m;
            float yin = y_k + h_k * (s_*th*th + d_k*t1m) / den;
            float num2 = d_k1*th*th + 2.f*s_*t1m + d_k*om*om;
            float ldin = 2.f*__logf(s_) + __logf(num2) - 2.f*__logf(den);

            *(float*)(smem + R4 + 8192 + (c*64 + lane)*4) = inside ? yin : xu;
            ld_acc += inside ? ldin : 0.f;
        }
    }

    // ---------------- epilogue ----------------
    __syncthreads();
    *(float*)(smem + R1 + (w*64 + lane)*4) = ld_acc;
    __syncthreads();
    if (t < 64){
        const float* lp = (const float*)(smem + R1);
        ldout[r0 + t] = (lp[t] + lp[64 + t]) + (lp[128 + t] + lp[192 + t]);
    }
    {
        int row = t >> 2, part = t & 3;
        const float* xrow = x + (size_t)(r0 + row)*64;
        float* yrow = yout + (size_t)(r0 + row)*64;
        const float* yu = (const float*)(smem + R4 + 8192);
        #pragma unroll
        for (int j = 0; j < 4; j++){
            int s = part*4 + j;
            float4 xv = ((const float4*)xrow)[s];
            float4 o;
            o.x = xv.x; o.z = xv.z;
            o.y = yu[(2*s)*64 + row];
            o.w = yu[(2*s+1)*64 + row];
            ((float4*)yrow)[s] = o;
        }
    }
}

extern "C" void kernel_launch(void* const* d_in, const int* in_sizes, int n_in,
                              void* d_out, int out_size, void* d_ws, size_t ws_size,
                              hipStream_t stream)
{
    const float* x   = (const float*)d_in[0];
    const float* W0  = (const float*)d_in[1];
    const float* b0  = (const float*)d_in[2];
    const float* g0  = (const float*)d_in[3];
    const float* be0 = (const float*)d_in[4];
    const float* W1  = (const float*)d_in[5];
    const float* b1  = (const float*)d_in[6];
    const float* g1  = (const float*)d_in[7];
    const float* be1 = (const float*)d_in[8];
    const float* Wp  = (const float*)d_in[9];
    const float* bp  = (const float*)d_in[10];
    float* y = (float*)d_out;
    float* ldo = y + (size_t)NROWS * 64;
    char* ws = (char*)d_ws;

    hipLaunchKernelGGL(prep_kernel, dim3(152), dim3(256), 0, stream, W0, W1, Wp, bp, ws);
    hipLaunchKernelGGL(main_kernel, dim3(4096), dim3(256), 0, stream,
                       x, b0, g0, be0, b1, g1, be1, ws, y, ldo);
}

// Round 3
// 501.846 us; speedup vs baseline: 1.1572x; 1.1572x over previous
//
#include <hip/hip_runtime.h>
#include <hip/hip_bf16.h>
#include <stdint.h>

#define NROWS 262144

typedef __bf16 bf16x8 __attribute__((ext_vector_type(8)));
typedef float f32x4 __attribute__((ext_vector_type(4)));

#define MFMA(a,b,c) __builtin_amdgcn_mfma_f32_16x16x32_bf16(a,b,c,0,0,0)

// ws images (byte-exact LDS images, staged linearly)
#define WS_W0 0          // 16KB: [plane][g:4][n:128] cells of 8 bf16 (k = g*8+j)
#define WS_W1 16384      // 64KB: 4 rounds kr, each [plane][q:4][n:128] (k = kr*32+q*8+j)
#define WS_WP 81920      // 512KB: 32 chunks d, each [plane][g:16][n:32] (k = g*8+j, col = d*32+n)
#define WS_BP 606208     // 4KB: bp padded 25->32 per dim

// LDS regions (64KB total)
#define RS0 0            // chunk/W1 staging buf A (16KB)
#define RS1 16384        // chunk/W1 staging buf B (16KB)
#define RING 32768       // phase3: raw ring 4 x 8KB. phases 0-2: xmA (8KB) + transpose (16KB), W0 at RING+16384

__device__ __forceinline__ unsigned short f2bf(float f){
    unsigned int u = __float_as_uint(f);
    u = (u + 0x7FFFu + ((u >> 16) & 1u)) >> 16;
    return (unsigned short)u;
}
__device__ __forceinline__ float bf2f(unsigned short h){
    return __uint_as_float(((unsigned int)h) << 16);
}

__global__ __launch_bounds__(256) void prep_kernel(
    const float* __restrict__ W0, const float* __restrict__ W1,
    const float* __restrict__ Wp, const float* __restrict__ bp,
    char* __restrict__ ws)
{
    int tid = blockIdx.x * 256 + threadIdx.x;   // grid 152 -> 38912 threads
    if (tid < 32768){                            // Wp chunks
        int d = tid >> 10, r = tid & 1023;
        int plane = r >> 9, g = (r >> 5) & 15, n = r & 31;
        unsigned short cell[8];
        #pragma unroll
        for (int j = 0; j < 8; j++){
            int k = g*8 + j;
            float v = (n < 25) ? Wp[k*800 + d*25 + n] : 0.f;
            unsigned short hi = f2bf(v);
            cell[j] = plane ? f2bf(v - bf2f(hi)) : hi;
        }
        *(uint4*)(ws + WS_WP + d*16384 + plane*8192 + (g*32+n)*16) = *(uint4*)cell;
    } else if (tid < 36864){                     // W1 rounds
        int i = tid - 32768;
        int kr = i >> 10, r = i & 1023;
        int plane = r >> 9, q = (r >> 7) & 3, n = r & 127;
        unsigned short cell[8];
        #pragma unroll
        for (int j = 0; j < 8; j++){
            int k = kr*32 + q*8 + j;
            float v = W1[k*128 + n];
            unsigned short hi = f2bf(v);
            cell[j] = plane ? f2bf(v - bf2f(hi)) : hi;
        }
        *(uint4*)(ws + WS_W1 + kr*16384 + plane*8192 + (q*128+n)*16) = *(uint4*)cell;
    } else if (tid < 37888){                     // W0
        int i = tid - 36864;
        int plane = i >> 9, g = (i >> 7) & 3, n = i & 127;
        unsigned short cell[8];
        #pragma unroll
        for (int j = 0; j < 8; j++){
            int k = g*8 + j;
            float v = W0[k*128 + n];
            unsigned short hi = f2bf(v);
            cell[j] = plane ? f2bf(v - bf2f(hi)) : hi;
        }
        *(uint4*)(ws + WS_W0 + plane*8192 + (g*128+n)*16) = *(uint4*)cell;
    } else if (tid < 38912){                     // bp padded
        int i = tid - 37888;
        int d = i >> 5, n = i & 31;
        ((float*)(ws + WS_BP))[i] = (n < 25) ? bp[d*25 + n] : 0.f;
    }
}

__global__ __launch_bounds__(256, 2) void main_kernel(
    const float* __restrict__ x,
    const float* __restrict__ pb0, const float* __restrict__ pg0, const float* __restrict__ pbe0,
    const float* __restrict__ pb1, const float* __restrict__ pg1, const float* __restrict__ pbe1,
    const char* __restrict__ ws,
    float* __restrict__ yout, float* __restrict__ ldout)
{
    __shared__ __align__(16) char smem[65536];
    const int t = threadIdx.x;
    const int r0 = blockIdx.x * 64;
    const int w = t >> 6, lane = t & 63, l16 = lane & 15, q = lane >> 4;
    const float* bpp = (const float*)(ws + WS_BP);
    const f32x4 fzero = {0.f, 0.f, 0.f, 0.f};

    auto stage16k = [&](int dstoff, int srcoff){
        #pragma unroll
        for (int k = 0; k < 4; k++){
            int cell = t + 256*k;
            ((uint4*)(smem + dstoff))[cell] = ((const uint4*)(ws + srcoff))[cell];
        }
    };

    // ---------------- phase 0: x -> xmA(hi/lo); stage W0, W1 kr0 ----------------
    #pragma unroll
    for (int k = 0; k < 4; k++){
        int i = t + 256*k;                 // 1024 float4s of the 64x64 x tile
        int row = i >> 4, s = i & 15;
        float4 v = ((const float4*)(x + (size_t)(r0 + row) * 64))[s];
        unsigned short h0 = f2bf(v.x), h1s = f2bf(v.z);
        unsigned short l0 = f2bf(v.x - bf2f(h0)), l1 = f2bf(v.z - bf2f(h1s));
        int g = s >> 2, ofs = (s & 3) * 4;
        *(unsigned int*)(smem + RING + (g*64 + row)*16 + ofs) = (unsigned int)h0 | ((unsigned int)h1s << 16);
        *(unsigned int*)(smem + RING + 4096 + (g*64 + row)*16 + ofs) = (unsigned int)l0 | ((unsigned int)l1 << 16);
    }
    stage16k(RING + 16384, WS_W0);
    stage16k(RS0, WS_W1);                  // W1 kr0
    __syncthreads();

    // ---------------- phase 1: GEMM0 (split bf16x3) + LN0 + relu ----------------
    float h1r[8][4];
    {
        bf16x8 a_h = *(const bf16x8*)(smem + RING + (q*64 + 16*w + l16)*16);
        bf16x8 a_l = *(const bf16x8*)(smem + RING + 4096 + (q*64 + 16*w + l16)*16);
        f32x4 c0[8];
        #pragma unroll
        for (int nt = 0; nt < 8; nt++){
            int n = nt*16 + l16;
            bf16x8 b_h = *(const bf16x8*)(smem + RING + 16384 + (q*128 + n)*16);
            bf16x8 b_l = *(const bf16x8*)(smem + RING + 16384 + 8192 + (q*128 + n)*16);
            f32x4 acc = fzero;
            acc = MFMA(a_h, b_l, acc);
            acc = MFMA(a_l, b_h, acc);
            acc = MFMA(a_h, b_h, acc);
            c0[nt] = acc;
        }
        float s1[4] = {0,0,0,0}, s2[4] = {0,0,0,0};
        #pragma unroll
        for (int nt = 0; nt < 8; nt++){
            float bv = pb0[nt*16 + l16];
            #pragma unroll
            for (int rg = 0; rg < 4; rg++){
                float v = c0[nt][rg] + bv;
                c0[nt][rg] = v; s1[rg] += v; s2[rg] += v*v;
            }
        }
        #pragma unroll
        for (int m = 1; m < 16; m <<= 1)
            #pragma unroll
            for (int rg = 0; rg < 4; rg++){
                s1[rg] += __shfl_xor(s1[rg], m, 64);
                s2[rg] += __shfl_xor(s2[rg], m, 64);
            }
        #pragma unroll
        for (int rg = 0; rg < 4; rg++){
            float mean = s1[rg] * 0.0078125f;
            float var  = s2[rg] * 0.0078125f - mean*mean;
            s1[rg] = mean; s2[rg] = rsqrtf(var + 1e-6f);
        }
        #pragma unroll
        for (int nt = 0; nt < 8; nt++){
            float gv = pg0[nt*16 + l16], bev = pbe0[nt*16 + l16];
            #pragma unroll
            for (int rg = 0; rg < 4; rg++){
                float hv = (c0[nt][rg] - s1[rg]) * s2[rg] * gv + bev;
                h1r[nt][rg] = fmaxf(hv, 0.f);
            }
        }
    }
    __syncthreads();   // xmA / W0 regions now free

    // stage W1 kr1 into RS1; wave-local transpose of h1 -> A-frag registers
    stage16k(RS1, WS_W1 + 16384);
    bf16x8 ah1[4], al1[4];
    {
        char* sb = smem + RING + w*4096;   // wave stripe: [g:16][row:16] cells
        #pragma unroll
        for (int nt = 0; nt < 8; nt++){
            int col = nt*16 + l16;
            #pragma unroll
            for (int rg = 0; rg < 4; rg++)
                *(unsigned short*)(sb + ((col>>3)*16 + q*4+rg)*16 + (col&7)*2) = f2bf(h1r[nt][rg]);
        }
        #pragma unroll
        for (int kr = 0; kr < 4; kr++)
            ah1[kr] = *(const bf16x8*)(sb + ((kr*4+q)*16 + l16)*16);
        #pragma unroll
        for (int nt = 0; nt < 8; nt++){
            int col = nt*16 + l16;
            #pragma unroll
            for (int rg = 0; rg < 4; rg++){
                unsigned short hi = f2bf(h1r[nt][rg]);
                *(unsigned short*)(sb + ((col>>3)*16 + q*4+rg)*16 + (col&7)*2) = f2bf(h1r[nt][rg] - bf2f(hi));
            }
        }
        #pragma unroll
        for (int kr = 0; kr < 4; kr++)
            al1[kr] = *(const bf16x8*)(sb + ((kr*4+q)*16 + l16)*16);
    }

    // ---------------- phase 2: GEMM1 (4 K-rounds, split bf16x3) ----------------
    f32x4 c1[8];
    #pragma unroll
    for (int nt = 0; nt < 8; nt++) c1[nt] = fzero;
    auto g1round = [&](int base, bf16x8 ah, bf16x8 al){
        #pragma unroll
        for (int nt = 0; nt < 8; nt++){
            int n = nt*16 + l16;
            bf16x8 bh = *(const bf16x8*)(smem + base + (q*128 + n)*16);
            bf16x8 bl = *(const bf16x8*)(smem + base + 8192 + (q*128 + n)*16);
            c1[nt] = MFMA(ah, bl, c1[nt]);
            c1[nt] = MFMA(al, bh, c1[nt]);
            c1[nt] = MFMA(ah, bh, c1[nt]);
        }
    };
    g1round(RS0, ah1[0], al1[0]);
    __syncthreads();
    stage16k(RS0, WS_W1 + 32768);          // kr2
    g1round(RS1, ah1[1], al1[1]);
    __syncthreads();
    stage16k(RS1, WS_W1 + 49152);          // kr3
    g1round(RS0, ah1[2], al1[2]);
    __syncthreads();
    g1round(RS1, ah1[3], al1[3]);

    // LN1 + relu + residual -> h2 (into h1r)
    {
        float s1[4] = {0,0,0,0}, s2[4] = {0,0,0,0};
        #pragma unroll
        for (int nt = 0; nt < 8; nt++){
            float bv = pb1[nt*16 + l16];
            #pragma unroll
            for (int rg = 0; rg < 4; rg++){
                float v = c1[nt][rg] + bv;
                c1[nt][rg] = v; s1[rg] += v; s2[rg] += v*v;
            }
        }
        #pragma unroll
        for (int m = 1; m < 16; m <<= 1)
            #pragma unroll
            for (int rg = 0; rg < 4; rg++){
                s1[rg] += __shfl_xor(s1[rg], m, 64);
                s2[rg] += __shfl_xor(s2[rg], m, 64);
            }
        #pragma unroll
        for (int rg = 0; rg < 4; rg++){
            float mean = s1[rg] * 0.0078125f;
            float var  = s2[rg] * 0.0078125f - mean*mean;
            s1[rg] = mean; s2[rg] = rsqrtf(var + 1e-6f);
        }
        #pragma unroll
        for (int nt = 0; nt < 8; nt++){
            float gv = pg1[nt*16 + l16], bev = pbe1[nt*16 + l16];
            #pragma unroll
            for (int rg = 0; rg < 4; rg++){
                float hv = (c1[nt][rg] - s1[rg]) * s2[rg] * gv + bev;
                h1r[nt][rg] = fmaxf(hv, 0.f) + h1r[nt][rg];
            }
        }
    }
    __syncthreads();   // all waves done with RS0/RS1 weight reads

    // h2 -> A-frag registers (wave-local); stage chunks 0/1
    bf16x8 ah2[4], al2[4];
    {
        char* sb = smem + RING + w*4096;
        #pragma unroll
        for (int nt = 0; nt < 8; nt++){
            int col = nt*16 + l16;
            #pragma unroll
            for (int rg = 0; rg < 4; rg++)
                *(unsigned short*)(sb + ((col>>3)*16 + q*4+rg)*16 + (col&7)*2) = f2bf(h1r[nt][rg]);
        }
        #pragma unroll
        for (int kr = 0; kr < 4; kr++)
            ah2[kr] = *(const bf16x8*)(sb + ((kr*4+q)*16 + l16)*16);
        #pragma unroll
        for (int nt = 0; nt < 8; nt++){
            int col = nt*16 + l16;
            #pragma unroll
            for (int rg = 0; rg < 4; rg++){
                unsigned short hi = f2bf(h1r[nt][rg]);
                *(unsigned short*)(sb + ((col>>3)*16 + q*4+rg)*16 + (col&7)*2) = f2bf(h1r[nt][rg] - bf2f(hi));
            }
        }
        #pragma unroll
        for (int kr = 0; kr < 4; kr++)
            al2[kr] = *(const bf16x8*)(sb + ((kr*4+q)*16 + l16)*16);
    }
    stage16k(RS0, WS_WP);                  // chunk 0
    stage16k(RS1, WS_WP + 16384);          // chunk 1
    __syncthreads();

    // ---------------- phase 3: 32 chunks, spline every 4 (all threads) ----------------
    float ld_acc = 0.f;
    float yureg[8];
    for (int c = 0; c < 32; c++){
        const char* cb = smem + ((c & 1) ? RS1 : RS0);
        float bpv0 = bpp[c*32 + l16];
        float bpv1 = bpp[c*32 + 16 + l16];
        f32x4 c2a = fzero, c2b = fzero;
        #pragma unroll
        for (int kb = 0; kb < 4; kb++){
            bf16x8 bh0 = *(const bf16x8*)(cb + ((kb*4+q)*32 + l16)*16);
            bf16x8 bl0 = *(const bf16x8*)(cb + 8192 + ((kb*4+q)*32 + l16)*16);
            bf16x8 bh1 = *(const bf16x8*)(cb + ((kb*4+q)*32 + 16 + l16)*16);
            bf16x8 bl1 = *(const bf16x8*)(cb + 8192 + ((kb*4+q)*32 + 16 + l16)*16);
            c2a = MFMA(ah2[kb], bl0, c2a); c2a = MFMA(al2[kb], bh0, c2a); c2a = MFMA(ah2[kb], bh0, c2a);
            c2b = MFMA(ah2[kb], bl1, c2b); c2b = MFMA(al2[kb], bh1, c2b); c2b = MFMA(ah2[kb], bh1, c2b);
        }
        {   // raw write to ring slot c&3: [row][8 groups x 16B], group swizzle g^(row&7)
            char* rb = smem + RING + (c & 3)*8192;
            #pragma unroll
            for (int rg = 0; rg < 4; rg++){
                int row = 16*w + q*4 + rg;
                int p0 = l16, p1 = 16 + l16;
                *(float*)(rb + row*128 + (((p0>>2) ^ (row&7))*16) + (p0&3)*4) = c2a[rg] + bpv0;
                *(float*)(rb + row*128 + (((p1>>2) ^ (row&7))*16) + (p1&3)*4) = c2b[rg] + bpv1;
            }
        }
        __syncthreads();
        if (c < 30) stage16k((c & 1) ? RS1 : RS0, WS_WP + (c+2)*16384);
        if ((c & 3) == 3){
            // spline: thread -> row = lane, slot = w, dim = 4*(c>>2) + w
            int g = c >> 2;
            int dim = 4*g + w;
            const char* rb = smem + RING + w*8192;
            float r[28];
            #pragma unroll
            for (int j = 0; j < 7; j++){
                float4 v4 = *(const float4*)(rb + lane*128 + ((j ^ (lane & 7))*16));
                r[4*j+0] = v4.x; r[4*j+1] = v4.y; r[4*j+2] = v4.z; r[4*j+3] = v4.w;
            }
            float mw = r[0];
            #pragma unroll
            for (int k = 1; k < 8; k++) mw = fmaxf(mw, r[k]);
            float ew[8], sm = 0.f;
            #pragma unroll
            for (int k = 0; k < 8; k++){ ew[k] = __expf(r[k] - mw); sm += ew[k]; }
            float si = 5.952f / sm;
            float wv[8];
            #pragma unroll
            for (int k = 0; k < 8; k++) wv[k] = 0.006f + ew[k] * si;
            mw = r[8];
            #pragma unroll
            for (int k = 1; k < 8; k++) mw = fmaxf(mw, r[8+k]);
            sm = 0.f;
            #pragma unroll
            for (int k = 0; k < 8; k++){ ew[k] = __expf(r[8+k] - mw); sm += ew[k]; }
            si = 5.952f / sm;
            float hv[8];
            #pragma unroll
            for (int k = 0; k < 8; k++) hv[k] = 0.006f + ew[k] * si;

            float xu = x[(size_t)(r0 + lane)*64 + 2*dim + 1];
            bool inside = (xu > -3.f) && (xu < 3.f);
            float xc = fminf(fmaxf(xu, -3.f), 3.f);
            float cwk = -3.f + wv[0], chk = -3.f + hv[0];
            float x_k = -3.f, y_k = -3.f, w_k = wv[0], h_k = hv[0];
            int idx = 0;
            #pragma unroll
            for (int k = 1; k < 8; k++){
                if (xc >= cwk){ x_k = cwk; y_k = chk; w_k = wv[k]; h_k = hv[k]; idx = k; }
                cwk += wv[k]; chk += hv[k];
            }
            float dkr = r[16], dk1r = r[17];
            #pragma unroll
            for (int k = 1; k < 8; k++)
                if (idx == k){ dkr = r[16+k]; dk1r = r[17+k]; }
            float d_k  = fmaxf(dkr, 0.f)  + __logf(1.f + __expf(-fabsf(dkr)))  + 0.001f;
            float d_k1 = fmaxf(dk1r, 0.f) + __logf(1.f + __expf(-fabsf(dk1r))) + 0.001f;
            float iw = 1.f / w_k;
            float s_ = h_k * iw;
            float th = (xc - x_k) * iw;
            float om = 1.f - th;
            float t1m = th * om;
            float den = s_ + (d_k1 + d_k - 2.f*s_) * t1m;
            float yin = y_k + h_k * (s_*th*th + d_k*t1m) / den;
            float num2 = d_k1*th*th + 2.f*s_*t1m + d_k*om*om;
            float ldin = 2.f*__logf(s_) + __logf(num2) - 2.f*__logf(den);

            yureg[g] = inside ? yin : xu;
            ld_acc += inside ? ldin : 0.f;
            __syncthreads();   // protect ring before next group's raw writes
        }
    }

    // ---------------- epilogue ----------------
    {   // yu regs -> LDS [dim:32][row:64] at RS0; ld partials -> RING
        float* yuL = (float*)(smem + RS0);
        #pragma unroll
        for (int g = 0; g < 8; g++)
            yuL[(4*g + w)*64 + lane] = yureg[g];
        *(float*)(smem + RING + (w*64 + lane)*4) = ld_acc;
    }
    __syncthreads();
    if (t < 64){
        const float* lp = (const float*)(smem + RING);
        ldout[r0 + t] = (lp[t] + lp[64 + t]) + (lp[128 + t] + lp[192 + t]);
    }
    {
        int row = t >> 2, part = t & 3;
        const float* xrow = x + (size_t)(r0 + row)*64;
        float* yrow = yout + (size_t)(r0 + row)*64;
        const float* yuL = (const float*)(smem + RS0);
        #pragma unroll
        for (int j = 0; j < 4; j++){
            int s = part*4 + j;
            float4 xv = ((const float4*)xrow)[s];
            float4 o;
            o.x = xv.x; o.z = xv.z;
            o.y = yuL[(2*s)*64 + row];
            o.w = yuL[(2*s+1)*64 + row];
            ((float4*)yrow)[s] = o;
        }
    }
}

extern "C" void kernel_launch(void* const* d_in, const int* in_sizes, int n_in,
                              void* d_out, int out_size, void* d_ws, size_t ws_size,
                              hipStream_t stream)
{
    const float* x   = (const float*)d_in[0];
    const float* W0  = (const float*)d_in[1];
    const float* b0  = (const float*)d_in[2];
    const float* g0  = (const float*)d_in[3];
    const float* be0 = (const float*)d_in[4];
    const float* W1  = (const float*)d_in[5];
    const float* b1  = (const float*)d_in[6];
    const float* g1  = (const float*)d_in[7];
    const float* be1 = (const float*)d_in[8];
    const float* Wp  = (const float*)d_in[9];
    const float* bp  = (const float*)d_in[10];
    float* y = (float*)d_out;
    float* ldo = y + (size_t)NROWS * 64;
    char* ws = (char*)d_ws;

    hipLaunchKernelGGL(prep_kernel, dim3(152), dim3(256), 0, stream, W0, W1, Wp, bp, ws);
    hipLaunchKernelGGL(main_kernel, dim3(4096), dim3(256), 0, stream,
                       x, b0, g0, be0, b1, g1, be1, ws, y, ldo);
}

// Round 4
// 410.539 us; speedup vs baseline: 1.4146x; 1.2224x over previous
//
#include <hip/hip_runtime.h>
#include <hip/hip_bf16.h>
#include <stdint.h>

#define NROWS 262144

typedef __bf16 bf16x8 __attribute__((ext_vector_type(8)));
typedef float f32x4 __attribute__((ext_vector_type(4)));
typedef float f32x16 __attribute__((ext_vector_type(16)));

#define MFMA16(a,b,c) __builtin_amdgcn_mfma_f32_16x16x32_bf16(a,b,c,0,0,0)
#define MFMA32(a,b,c) __builtin_amdgcn_mfma_f32_32x32x16_bf16(a,b,c,0,0,0)

// ws images
#define WS_WP 0          // 512KB: d*16384 + plane*8192 + oct*512 + p*16 + j*2  (k = oct*8+j, p<32)
#define WS_W1 524288     // 64KB:  kr*16384 + plane*8192 + (q*128+n)*16        (k = kr*32+q*8+j)
#define WS_W0 589824     // 16KB:  plane*8192 + (g*128+n)*16                   (k = g*8+j)
#define WS_BP 606208     // 4KB:   bp padded 25->32 per dim

// LDS (64KB): RS0/RS1 = W1 staging dbuf, later h2_hi/h2_lo planes.
// 32768..40960 xmA hi/lo (phase0-1) -> h1 stripes w0/w1 (phase2) -> yuL (phase3)
// 40960..57344 W0 (phase0-1)        -> h1 stripes w2/w3 (phase2) -> ldL @49152 (epilogue)
// 57344..65536 xuL [dim:32][row:64] f32 (persistent phase0 -> phase3)
#define RS0 0
#define RS1 16384
#define XMA 32768
#define W0L 40960
#define YUL 32768
#define LDL 49152
#define XUL 57344

__device__ __forceinline__ unsigned short f2bf(float f){
    unsigned int u = __float_as_uint(f);
    u = (u + 0x7FFFu + ((u >> 16) & 1u)) >> 16;
    return (unsigned short)u;
}
__device__ __forceinline__ float bf2f(unsigned short h){
    return __uint_as_float(((unsigned int)h) << 16);
}

__global__ __launch_bounds__(256) void prep_kernel(
    const float* __restrict__ W0, const float* __restrict__ W1,
    const float* __restrict__ Wp, const float* __restrict__ bp,
    char* __restrict__ ws)
{
    int tid = blockIdx.x * 256 + threadIdx.x;   // grid 152 -> 38912 threads
    if (tid < 32768){                            // Wp: A-operand frag image for 32x32x16
        int d = tid >> 10, r = tid & 1023;
        int plane = r >> 9, oct = (r >> 5) & 15, p = r & 31;
        unsigned short cell[8];
        #pragma unroll
        for (int j = 0; j < 8; j++){
            int k = oct*8 + j;
            float v = (p < 25) ? Wp[k*800 + d*25 + p] : 0.f;
            unsigned short hi = f2bf(v);
            cell[j] = plane ? f2bf(v - bf2f(hi)) : hi;
        }
        *(uint4*)(ws + WS_WP + d*16384 + plane*8192 + oct*512 + p*16) = *(uint4*)cell;
    } else if (tid < 36864){                     // W1 rounds
        int i = tid - 32768;
        int kr = i >> 10, r = i & 1023;
        int plane = r >> 9, q = (r >> 7) & 3, n = r & 127;
        unsigned short cell[8];
        #pragma unroll
        for (int j = 0; j < 8; j++){
            int k = kr*32 + q*8 + j;
            float v = W1[k*128 + n];
            unsigned short hi = f2bf(v);
            cell[j] = plane ? f2bf(v - bf2f(hi)) : hi;
        }
        *(uint4*)(ws + WS_W1 + kr*16384 + plane*8192 + (q*128+n)*16) = *(uint4*)cell;
    } else if (tid < 37888){                     // W0
        int i = tid - 36864;
        int plane = i >> 9, g = (i >> 7) & 3, n = i & 127;
        unsigned short cell[8];
        #pragma unroll
        for (int j = 0; j < 8; j++){
            int k = g*8 + j;
            float v = W0[k*128 + n];
            unsigned short hi = f2bf(v);
            cell[j] = plane ? f2bf(v - bf2f(hi)) : hi;
        }
        *(uint4*)(ws + WS_W0 + plane*8192 + (g*128+n)*16) = *(uint4*)cell;
    } else if (tid < 38912){                     // bp padded
        int i = tid - 37888;
        int d = i >> 5, n = i & 31;
        ((float*)(ws + WS_BP))[i] = (n < 25) ? bp[d*25 + n] : 0.f;
    }
}

__global__ __launch_bounds__(256, 2) void main_kernel(
    const float* __restrict__ x,
    const float* __restrict__ pb0, const float* __restrict__ pg0, const float* __restrict__ pbe0,
    const float* __restrict__ pb1, const float* __restrict__ pg1, const float* __restrict__ pbe1,
    const char* __restrict__ ws,
    float* __restrict__ yout, float* __restrict__ ldout)
{
    __shared__ __align__(16) char smem[65536];
    const int t = threadIdx.x;
    const int r0 = blockIdx.x * 64;
    const int w = t >> 6, lane = t & 63, l16 = lane & 15, q = lane >> 4;
    const f32x4 fzero = {0.f, 0.f, 0.f, 0.f};

    auto stage16k = [&](int dstoff, int srcoff){
        #pragma unroll
        for (int k = 0; k < 4; k++){
            int cell = t + 256*k;
            ((uint4*)(smem + dstoff))[cell] = ((const uint4*)(ws + srcoff))[cell];
        }
    };

    // ---------------- phase 0: x -> xmA(hi/lo) + xuL; stage W0, W1 kr0 ----------------
    #pragma unroll
    for (int k = 0; k < 4; k++){
        int i = t + 256*k;
        int row = i >> 4, s = i & 15;
        float4 v = ((const float4*)(x + (size_t)(r0 + row) * 64))[s];
        unsigned short h0 = f2bf(v.x), h1s = f2bf(v.z);
        unsigned short l0 = f2bf(v.x - bf2f(h0)), l1 = f2bf(v.z - bf2f(h1s));
        int g = s >> 2, ofs = (s & 3) * 4;
        *(unsigned int*)(smem + XMA + (g*64 + row)*16 + ofs) = (unsigned int)h0 | ((unsigned int)h1s << 16);
        *(unsigned int*)(smem + XMA + 4096 + (g*64 + row)*16 + ofs) = (unsigned int)l0 | ((unsigned int)l1 << 16);
        *(float*)(smem + XUL + ((2*s)*64 + row)*4) = v.y;
        *(float*)(smem + XUL + ((2*s+1)*64 + row)*4) = v.w;
    }
    stage16k(W0L, WS_W0);
    stage16k(RS0, WS_W1);                  // kr0
    __syncthreads();

    // ---------------- phase 1: GEMM0 (split bf16x3, 16x16x32) + LN0 + relu ----------------
    float h1r[8][4];
    {
        bf16x8 a_h = *(const bf16x8*)(smem + XMA + (q*64 + 16*w + l16)*16);
        bf16x8 a_l = *(const bf16x8*)(smem + XMA + 4096 + (q*64 + 16*w + l16)*16);
        f32x4 c0[8];
        #pragma unroll
        for (int nt = 0; nt < 8; nt++){
            int n = nt*16 + l16;
            bf16x8 b_h = *(const bf16x8*)(smem + W0L + (q*128 + n)*16);
            bf16x8 b_l = *(const bf16x8*)(smem + W0L + 8192 + (q*128 + n)*16);
            f32x4 acc = fzero;
            acc = MFMA16(a_h, b_l, acc);
            acc = MFMA16(a_l, b_h, acc);
            acc = MFMA16(a_h, b_h, acc);
            c0[nt] = acc;
        }
        float s1[4] = {0,0,0,0}, s2[4] = {0,0,0,0};
        #pragma unroll
        for (int nt = 0; nt < 8; nt++){
            float bv = pb0[nt*16 + l16];
            #pragma unroll
            for (int rg = 0; rg < 4; rg++){
                float v = c0[nt][rg] + bv;
                c0[nt][rg] = v; s1[rg] += v; s2[rg] += v*v;
            }
        }
        #pragma unroll
        for (int m = 1; m < 16; m <<= 1)
            #pragma unroll
            for (int rg = 0; rg < 4; rg++){
                s1[rg] += __shfl_xor(s1[rg], m, 64);
                s2[rg] += __shfl_xor(s2[rg], m, 64);
            }
        #pragma unroll
        for (int rg = 0; rg < 4; rg++){
            float mean = s1[rg] * 0.0078125f;
            float var  = s2[rg] * 0.0078125f - mean*mean;
            s1[rg] = mean; s2[rg] = rsqrtf(var + 1e-6f);
        }
        #pragma unroll
        for (int nt = 0; nt < 8; nt++){
            float gv = pg0[nt*16 + l16], bev = pbe0[nt*16 + l16];
            #pragma unroll
            for (int rg = 0; rg < 4; rg++){
                float hv = (c0[nt][rg] - s1[rg]) * s2[rg] * gv + bev;
                h1r[nt][rg] = fmaxf(hv, 0.f);
            }
        }
    }
    __syncthreads();   // xmA / W0 now free

    // stage W1 kr1 into RS1; wave-local transpose of h1 -> A-frag registers
    stage16k(RS1, WS_W1 + 16384);
    bf16x8 ah1[4], al1[4];
    {
        char* sb = smem + 32768 + w*4096;
        #pragma unroll
        for (int nt = 0; nt < 8; nt++){
            int col = nt*16 + l16;
            #pragma unroll
            for (int rg = 0; rg < 4; rg++)
                *(unsigned short*)(sb + ((col>>3)*16 + q*4+rg)*16 + (col&7)*2) = f2bf(h1r[nt][rg]);
        }
        #pragma unroll
        for (int kr = 0; kr < 4; kr++)
            ah1[kr] = *(const bf16x8*)(sb + ((kr*4+q)*16 + l16)*16);
        #pragma unroll
        for (int nt = 0; nt < 8; nt++){
            int col = nt*16 + l16;
            #pragma unroll
            for (int rg = 0; rg < 4; rg++){
                unsigned short hi = f2bf(h1r[nt][rg]);
                *(unsigned short*)(sb + ((col>>3)*16 + q*4+rg)*16 + (col&7)*2) = f2bf(h1r[nt][rg] - bf2f(hi));
            }
        }
        #pragma unroll
        for (int kr = 0; kr < 4; kr++)
            al1[kr] = *(const bf16x8*)(sb + ((kr*4+q)*16 + l16)*16);
    }

    // ---------------- phase 2: GEMM1 (4 K-rounds, split bf16x3) ----------------
    f32x4 c1[8];
    #pragma unroll
    for (int nt = 0; nt < 8; nt++) c1[nt] = fzero;
    auto g1round = [&](int base, bf16x8 ah, bf16x8 al){
        #pragma unroll
        for (int nt = 0; nt < 8; nt++){
            int n = nt*16 + l16;
            bf16x8 bhv = *(const bf16x8*)(smem + base + (q*128 + n)*16);
            bf16x8 blv = *(const bf16x8*)(smem + base + 8192 + (q*128 + n)*16);
            c1[nt] = MFMA16(ah, blv, c1[nt]);
            c1[nt] = MFMA16(al, bhv, c1[nt]);
            c1[nt] = MFMA16(ah, bhv, c1[nt]);
        }
    };
    g1round(RS0, ah1[0], al1[0]);
    __syncthreads();
    stage16k(RS0, WS_W1 + 32768);          // kr2
    g1round(RS1, ah1[1], al1[1]);
    __syncthreads();
    stage16k(RS1, WS_W1 + 49152);          // kr3
    g1round(RS0, ah1[2], al1[2]);
    __syncthreads();
    g1round(RS1, ah1[3], al1[3]);

    // LN1 + relu + residual -> h2 (into h1r)
    {
        float s1[4] = {0,0,0,0}, s2[4] = {0,0,0,0};
        #pragma unroll
        for (int nt = 0; nt < 8; nt++){
            float bv = pb1[nt*16 + l16];
            #pragma unroll
            for (int rg = 0; rg < 4; rg++){
                float v = c1[nt][rg] + bv;
                c1[nt][rg] = v; s1[rg] += v; s2[rg] += v*v;
            }
        }
        #pragma unroll
        for (int m = 1; m < 16; m <<= 1)
            #pragma unroll
            for (int rg = 0; rg < 4; rg++){
                s1[rg] += __shfl_xor(s1[rg], m, 64);
                s2[rg] += __shfl_xor(s2[rg], m, 64);
            }
        #pragma unroll
        for (int rg = 0; rg < 4; rg++){
            float mean = s1[rg] * 0.0078125f;
            float var  = s2[rg] * 0.0078125f - mean*mean;
            s1[rg] = mean; s2[rg] = rsqrtf(var + 1e-6f);
        }
        #pragma unroll
        for (int nt = 0; nt < 8; nt++){
            float gv = pg1[nt*16 + l16], bev = pbe1[nt*16 + l16];
            #pragma unroll
            for (int rg = 0; rg < 4; rg++){
                float hv = (c1[nt][rg] - s1[rg]) * s2[rg] * gv + bev;
                h1r[nt][rg] = fmaxf(hv, 0.f) + h1r[nt][rg];
            }
        }
    }
    __syncthreads();   // all waves done reading RS0/RS1 (W1)

    // ---------------- h2 -> block-wide transposed planes -> B-frag registers ----------------
    #pragma unroll
    for (int nt = 0; nt < 8; nt++){
        int k = nt*16 + l16;
        #pragma unroll
        for (int rg = 0; rg < 4; rg++){
            int row = 16*w + q*4 + rg;
            float val = h1r[nt][rg];
            unsigned short hi = f2bf(val);
            int addr = row*256 + ((((k>>3) ^ (row&15)) & 15)*16) + (k&7)*2;
            *(unsigned short*)(smem + RS0 + addr) = hi;
            *(unsigned short*)(smem + RS1 + addr) = f2bf(val - bf2f(hi));
        }
    }
    __syncthreads();
    bf16x8 bh[2][8], bl[2][8];
    #pragma unroll
    for (int T = 0; T < 2; T++)
        #pragma unroll
        for (int kb = 0; kb < 8; kb++){
            int r = T*32 + (lane & 31);
            int oct = kb*2 + (lane >> 5);
            int addr = r*256 + (((oct ^ (r&15)) & 15)*16);
            bh[T][kb] = *(const bf16x8*)(smem + RS0 + addr);
            bl[T][kb] = *(const bf16x8*)(smem + RS1 + addr);
        }

    // ---------------- phase 3: wave-independent, 8 dims/wave, no barriers ----------------
    const char* wpl = ws + WS_WP + lane*16;
    const float* bpf = (const float*)(ws + WS_BP);
    float* xuLf = (float*)(smem + XUL);
    float* yuLf = (float*)(smem + YUL);
    const uint4 zero4 = {0,0,0,0};
    const bool pok = (lane & 31) < 25;
    const int hh = lane >> 5;
    const int d0 = w*8;
    uint4 A0[8], A1[8];
    #pragma unroll
    for (int kk = 0; kk < 8; kk++){ A0[kk] = zero4; A1[kk] = zero4; }
    if (pok){
        #pragma unroll
        for (int kk = 0; kk < 4; kk++){
            A0[kk]   = *(const uint4*)(wpl + d0*16384 + kk*1024);
            A0[4+kk] = *(const uint4*)(wpl + d0*16384 + 8192 + kk*1024);
        }
    }
    float ld_acc = 0.f;
    for (int i = 0; i < 8; i++){
        int c = d0 + i;
        if (pok){
            #pragma unroll
            for (int kk = 0; kk < 4; kk++){
                A1[kk]   = *(const uint4*)(wpl + c*16384 + (4+kk)*1024);
                A1[4+kk] = *(const uint4*)(wpl + c*16384 + 8192 + (4+kk)*1024);
            }
        }
        f32x16 t0, t1;
        #pragma unroll
        for (int z = 0; z < 16; z++){ t0[z] = 0.f; t1[z] = 0.f; }
        #pragma unroll
        for (int kk = 0; kk < 4; kk++){
            bf16x8 ahh = *(bf16x8*)&A0[kk];
            bf16x8 all = *(bf16x8*)&A0[4+kk];
            t0 = MFMA32(ahh, bl[0][kk], t0); t1 = MFMA32(ahh, bl[1][kk], t1);
            t0 = MFMA32(all, bh[0][kk], t0); t1 = MFMA32(all, bh[1][kk], t1);
            t0 = MFMA32(ahh, bh[0][kk], t0); t1 = MFMA32(ahh, bh[1][kk], t1);
        }
        if (i < 7 && pok){
            #pragma unroll
            for (int kk = 0; kk < 4; kk++){
                A0[kk]   = *(const uint4*)(wpl + (c+1)*16384 + kk*1024);
                A0[4+kk] = *(const uint4*)(wpl + (c+1)*16384 + 8192 + kk*1024);
            }
        }
        #pragma unroll
        for (int kk = 0; kk < 4; kk++){
            bf16x8 ahh = *(bf16x8*)&A1[kk];
            bf16x8 all = *(bf16x8*)&A1[4+kk];
            t0 = MFMA32(ahh, bl[0][4+kk], t0); t1 = MFMA32(ahh, bl[1][4+kk], t1);
            t0 = MFMA32(all, bh[0][4+kk], t0); t1 = MFMA32(all, bh[1][4+kk], t1);
            t0 = MFMA32(ahh, bh[0][4+kk], t0); t1 = MFMA32(ahh, bh[1][4+kk], t1);
        }
        // ---- pairwise spline: lanes (L, L^32) jointly handle rows L&31 (tile0) and 32+(L&31) (tile1)
        float xu0 = xuLf[c*64 + (lane & 31)];
        float xu1 = xuLf[c*64 + 32 + (lane & 31)];
        float xc0 = fminf(fmaxf(xu0, -3.f), 3.f);
        float xc1 = fminf(fmaxf(xu1, -3.f), 3.f);
        float4 bq0 = *(const float4*)(bpf + c*32 + 0  + 4*hh);
        float4 bq1 = *(const float4*)(bpf + c*32 + 8  + 4*hh);
        float4 bq2 = *(const float4*)(bpf + c*32 + 16 + 4*hh);
        float  bq3 = bpf[c*32 + 24 + 4*hh];
        float wv0[4], wv1[4], hv0[4], hv1[4], dv0[4], dv1[4];
        #pragma unroll
        for (int jj = 0; jj < 4; jj++){
            wv0[jj] = t0[jj] + bq0[jj];  hv0[jj] = t0[4+jj] + bq1[jj];  dv0[jj] = t0[8+jj] + bq2[jj];
            wv1[jj] = t1[jj] + bq0[jj];  hv1[jj] = t1[4+jj] + bq1[jj];  dv1[jj] = t1[8+jj] + bq2[jj];
        }
        float dx0 = t0[12] + bq3, dx1 = t1[12] + bq3;
        float bd0 = __shfl_xor(hh ? dv0[0] : dx0, 32, 64);  // my role's boundary deriv raw (tile0)
        float bd1 = __shfl_xor(hh ? dv1[0] : dx1, 32, 64);
        auto softscale = [&](float* a){
            float m = fmaxf(fmaxf(a[0],a[1]), fmaxf(a[2],a[3]));
            m = fmaxf(m, __shfl_xor(m, 32, 64));
            float e0 = __expf(a[0]-m), e1 = __expf(a[1]-m), e2 = __expf(a[2]-m), e3 = __expf(a[3]-m);
            float s = (e0+e1)+(e2+e3);
            s += __shfl_xor(s, 32, 64);
            float sc = 5.952f / s;
            a[0] = fmaf(e0, sc, 0.006f); a[1] = fmaf(e1, sc, 0.006f);
            a[2] = fmaf(e2, sc, 0.006f); a[3] = fmaf(e3, sc, 0.006f);
        };
        softscale(wv0); softscale(hv0); softscale(wv1); softscale(hv1);
        auto candf = [&](float* wv, float* hv, float* dv, float bdr, float xc,
                         float& X, float& Y, float& W, float& H, float& DK, float& DK1, float& V){
            float pw0 = wv[0], pw1 = pw0+wv[1], pw2 = pw1+wv[2], pw3 = pw2+wv[3];
            float ph0 = hv[0], ph1 = ph0+hv[1], ph2 = ph1+hv[2], ph3 = ph2+hv[3];
            float offw = __shfl_xor(pw3, 32, 64);
            float offh = __shfl_xor(ph3, 32, 64);
            float bw = hh ? (offw - 3.f) : -3.f;
            float by = hh ? (offh - 3.f) : -3.f;
            X = bw; Y = by; W = wv[0]; H = hv[0]; DK = dv[0]; DK1 = dv[1];
            float e1_ = bw + pw0, e2_ = bw + pw1, e3_ = bw + pw2;
            if (xc >= e1_){ X = e1_; Y = by + ph0; W = wv[1]; H = hv[1]; DK = dv[1]; DK1 = dv[2]; }
            if (xc >= e2_){ X = e2_; Y = by + ph1; W = wv[2]; H = hv[2]; DK = dv[2]; DK1 = dv[3]; }
            if (xc >= e3_){ X = e3_; Y = by + ph2; W = wv[3]; H = hv[3]; DK = dv[3]; DK1 = bdr;  }
            V = (!hh || xc >= bw) ? 1.f : 0.f;
        };
        float X0,Y0,Wc0,Hc0,K0,K10,V0, X1,Y1,Wc1,Hc1,K1,K11,V1;
        candf(wv0, hv0, dv0, bd0, xc0, X0,Y0,Wc0,Hc0,K0,K10,V0);
        candf(wv1, hv1, dv1, bd1, xc1, X1,Y1,Wc1,Hc1,K1,K11,V1);
        // exchange the candidate of the tile I do NOT finalize (hh==0 -> tile1, hh==1 -> tile0)
        float rX  = __shfl_xor(hh ? X0  : X1 , 32, 64);
        float rY  = __shfl_xor(hh ? Y0  : Y1 , 32, 64);
        float rW  = __shfl_xor(hh ? Wc0 : Wc1, 32, 64);
        float rH  = __shfl_xor(hh ? Hc0 : Hc1, 32, 64);
        float rK  = __shfl_xor(hh ? K0  : K1 , 32, 64);
        float rK1 = __shfl_xor(hh ? K10 : K11, 32, 64);
        float rV  = __shfl_xor(hh ? V0  : V1 , 32, 64);
        float oX  = hh ? X1  : X0,  oY  = hh ? Y1  : Y0,  oW = hh ? Wc1 : Wc0;
        float oH  = hh ? Hc1 : Hc0, oK  = hh ? K1  : K0,  oK1 = hh ? K11 : K10;
        float oV  = hh ? V1  : V0;
        // h1-role candidate validity decides; own role == hh
        bool useh1 = ((hh ? oV : rV) > 0.5f);
        bool useOwn = (hh != 0) == useh1;
        float X = useOwn ? oX : rX,  Y = useOwn ? oY : rY;
        float W = useOwn ? oW : rW,  H = useOwn ? oH : rH;
        float K = useOwn ? oK : rK,  K1s = useOwn ? oK1 : rK1;
        float xu = hh ? xu1 : xu0;
        float xc = hh ? xc1 : xc0;
        float DKs  = fmaxf(K, 0.f)   + __logf(1.f + __expf(-fabsf(K)))   + 0.001f;
        float DK1s = fmaxf(K1s, 0.f) + __logf(1.f + __expf(-fabsf(K1s))) + 0.001f;
        float iw = 1.f / W;
        float s_ = H * iw;
        float th = (xc - X) * iw;
        float om = 1.f - th;
        float t1m = th * om;
        float den = s_ + (DK1s + DKs - 2.f*s_) * t1m;
        float yin = Y + H * (s_*th*th + DKs*t1m) / den;
        float num2 = DK1s*th*th + 2.f*s_*t1m + DKs*om*om;
        float ldin = 2.f*__logf(s_) + __logf(num2) - 2.f*__logf(den);
        bool inside = (xu > -3.f) && (xu < 3.f);
        yuLf[c*64 + lane] = inside ? yin : xu;   // lane L finalizes global row L
        ld_acc += inside ? ldin : 0.f;
    }

    // ---------------- epilogue ----------------
    *(float*)(smem + LDL + (w*64 + lane)*4) = ld_acc;
    __syncthreads();
    if (t < 64){
        const float* lp = (const float*)(smem + LDL);
        ldout[r0 + t] = (lp[t] + lp[64 + t]) + (lp[128 + t] + lp[192 + t]);
    }
    {
        int row = t >> 2, part = t & 3;
        const float* xrow = x + (size_t)(r0 + row)*64;
        float* yrow = yout + (size_t)(r0 + row)*64;
        const float* yuL = (const float*)(smem + YUL);
        #pragma unroll
        for (int j = 0; j < 4; j++){
            int s = part*4 + j;
            float4 xv = ((const float4*)xrow)[s];
            float4 o;
            o.x = xv.x; o.z = xv.z;
            o.y = yuL[(2*s)*64 + row];
            o.w = yuL[(2*s+1)*64 + row];
            ((float4*)yrow)[s] = o;
        }
    }
}

extern "C" void kernel_launch(void* const* d_in, const int* in_sizes, int n_in,
                              void* d_out, int out_size, void* d_ws, size_t ws_size,
                              hipStream_t stream)
{
    const float* x   = (const float*)d_in[0];
    const float* W0  = (const float*)d_in[1];
    const float* b0  = (const float*)d_in[2];
    const float* g0  = (const float*)d_in[3];
    const float* be0 = (const float*)d_in[4];
    const float* W1  = (const float*)d_in[5];
    const float* b1  = (const float*)d_in[6];
    const float* g1  = (const float*)d_in[7];
    const float* be1 = (const float*)d_in[8];
    const float* Wp  = (const float*)d_in[9];
    const float* bp  = (const float*)d_in[10];
    float* y = (float*)d_out;
    float* ldo = y + (size_t)NROWS * 64;
    char* ws = (char*)d_ws;

    hipLaunchKernelGGL(prep_kernel, dim3(152), dim3(256), 0, stream, W0, W1, Wp, bp, ws);
    hipLaunchKernelGGL(main_kernel, dim3(4096), dim3(256), 0, stream,
                       x, b0, g0, be0, b1, g1, be1, ws, y, ldo);
}

// Round 6
// 389.686 us; speedup vs baseline: 1.4903x; 1.0535x over previous
//
#include <hip/hip_runtime.h>
#include <hip/hip_bf16.h>
#include <stdint.h>

#define NROWS 262144

typedef __bf16 bf16x8 __attribute__((ext_vector_type(8)));
typedef float f32x4 __attribute__((ext_vector_type(4)));
typedef float f32x16 __attribute__((ext_vector_type(16)));

#define MFMA16(a,b,c) __builtin_amdgcn_mfma_f32_16x16x32_bf16(a,b,c,0,0,0)
#define MFMA32(a,b,c) __builtin_amdgcn_mfma_f32_32x32x16_bf16(a,b,c,0,0,0)

// ws images (identical to R4)
#define WS_WP 0          // 512KB: d*16384 + plane*8192 + oct*512 + p*16 (A-frag image, 32x32x16)
#define WS_W1 524288     // 64KB:  kr*16384 + plane*8192 + (q*128+n)*16
#define WS_W0 589824     // 16KB:  plane*8192 + (g*128+n)*16
#define WS_BP 606208     // 4KB:   bp padded 25->32 per dim (f32)

// LDS (49152 B -> 3 blocks/CU):
//  W1A @0      16KB: W1 kr0, then kr2; phase3 h2 hi plane
//  W1B @16384  16KB: W1 kr1, then kr3; phase3 h2 lo plane
//  XM  @32768   8KB: xm hi/lo planes -> h1 stripe scratch (2KB/wave) -> yu
//  XU  @40960   8KB: xu [dim:32][row:64] f32 -> ld partials (epilogue)
#define W1A 0
#define W1B 16384
#define XM  32768
#define XU  40960

__device__ __forceinline__ unsigned short f2bf(float f){
    unsigned int u = __float_as_uint(f);
    u = (u + 0x7FFFu + ((u >> 16) & 1u)) >> 16;
    return (unsigned short)u;
}
__device__ __forceinline__ float bf2f(unsigned short h){
    return __uint_as_float(((unsigned int)h) << 16);
}

__global__ __launch_bounds__(256) void prep_kernel(
    const float* __restrict__ W0, const float* __restrict__ W1,
    const float* __restrict__ Wp, const float* __restrict__ bp,
    char* __restrict__ ws)
{
    int tid = blockIdx.x * 256 + threadIdx.x;   // grid 152 -> 38912 threads
    if (tid < 32768){                            // Wp A-frag image
        int d = tid >> 10, r = tid & 1023;
        int plane = r >> 9, oct = (r >> 5) & 15, p = r & 31;
        unsigned short cell[8];
        #pragma unroll
        for (int j = 0; j < 8; j++){
            int k = oct*8 + j;
            float v = (p < 25) ? Wp[k*800 + d*25 + p] : 0.f;
            unsigned short hi = f2bf(v);
            cell[j] = plane ? f2bf(v - bf2f(hi)) : hi;
        }
        *(uint4*)(ws + WS_WP + d*16384 + plane*8192 + oct*512 + p*16) = *(uint4*)cell;
    } else if (tid < 36864){                     // W1 rounds
        int i = tid - 32768;
        int kr = i >> 10, r = i & 1023;
        int plane = r >> 9, q = (r >> 7) & 3, n = r & 127;
        unsigned short cell[8];
        #pragma unroll
        for (int j = 0; j < 8; j++){
            int k = kr*32 + q*8 + j;
            float v = W1[k*128 + n];
            unsigned short hi = f2bf(v);
            cell[j] = plane ? f2bf(v - bf2f(hi)) : hi;
        }
        *(uint4*)(ws + WS_W1 + kr*16384 + plane*8192 + (q*128+n)*16) = *(uint4*)cell;
    } else if (tid < 37888){                     // W0
        int i = tid - 36864;
        int plane = i >> 9, g = (i >> 7) & 3, n = i & 127;
        unsigned short cell[8];
        #pragma unroll
        for (int j = 0; j < 8; j++){
            int k = g*8 + j;
            float v = W0[k*128 + n];
            unsigned short hi = f2bf(v);
            cell[j] = plane ? f2bf(v - bf2f(hi)) : hi;
        }
        *(uint4*)(ws + WS_W0 + plane*8192 + (g*128+n)*16) = *(uint4*)cell;
    } else if (tid < 38912){                     // bp padded
        int i = tid - 37888;
        int d = i >> 5, n = i & 31;
        ((float*)(ws + WS_BP))[i] = (n < 25) ? bp[d*25 + n] : 0.f;
    }
}

__global__ __launch_bounds__(256, 3) void main_kernel(
    const float* __restrict__ x,
    const float* __restrict__ pb0, const float* __restrict__ pg0, const float* __restrict__ pbe0,
    const float* __restrict__ pb1, const float* __restrict__ pg1, const float* __restrict__ pbe1,
    const char* __restrict__ ws,
    float* __restrict__ yout, float* __restrict__ ldout)
{
    __shared__ __align__(16) char smem[49152];
    const int t = threadIdx.x;
    const int r0 = blockIdx.x * 64;
    const int w = t >> 6, lane = t & 63, l16 = lane & 15, q = lane >> 4;
    const f32x4 fzero = {0.f, 0.f, 0.f, 0.f};

    auto stage16k = [&](int dstoff, int srcoff){
        #pragma unroll
        for (int k = 0; k < 4; k++){
            int cell = t + 256*k;
            ((uint4*)(smem + dstoff))[cell] = ((const uint4*)(ws + srcoff))[cell];
        }
    };

    // ---------------- phase 0: W0 frags direct from L2; x -> xm/xu; stage W1 kr0+kr1 ----------------
    uint4 w0h[8], w0l[8];
    #pragma unroll
    for (int nt = 0; nt < 8; nt++){
        int n = nt*16 + l16;
        w0h[nt] = *(const uint4*)(ws + WS_W0 + (q*128 + n)*16);
        w0l[nt] = *(const uint4*)(ws + WS_W0 + 8192 + (q*128 + n)*16);
    }
    #pragma unroll
    for (int k = 0; k < 4; k++){
        int i = t + 256*k;
        int row = i >> 4, s = i & 15;
        float4 v = ((const float4*)(x + (size_t)(r0 + row) * 64))[s];
        unsigned short h0 = f2bf(v.x), h1s = f2bf(v.z);
        unsigned short l0 = f2bf(v.x - bf2f(h0)), l1 = f2bf(v.z - bf2f(h1s));
        int g = s >> 2, ofs = (s & 3) * 4;
        *(unsigned int*)(smem + XM + (g*64 + row)*16 + ofs) = (unsigned int)h0 | ((unsigned int)h1s << 16);
        *(unsigned int*)(smem + XM + 4096 + (g*64 + row)*16 + ofs) = (unsigned int)l0 | ((unsigned int)l1 << 16);
        *(float*)(smem + XU + ((2*s)*64 + row)*4) = v.y;
        *(float*)(smem + XU + ((2*s+1)*64 + row)*4) = v.w;
    }
    stage16k(W1A, WS_W1);                  // kr0
    stage16k(W1B, WS_W1 + 16384);          // kr1
    __syncthreads();

    // ---------------- phase 1: GEMM0 (split bf16x3) + LN0 + relu ----------------
    float h1r[8][4];
    {
        bf16x8 a_h = *(const bf16x8*)(smem + XM + (q*64 + 16*w + l16)*16);
        bf16x8 a_l = *(const bf16x8*)(smem + XM + 4096 + (q*64 + 16*w + l16)*16);
        f32x4 c0[8];
        #pragma unroll
        for (int nt = 0; nt < 8; nt++){
            bf16x8 b_h = *(bf16x8*)&w0h[nt];
            bf16x8 b_l = *(bf16x8*)&w0l[nt];
            f32x4 acc = fzero;
            acc = MFMA16(a_h, b_l, acc);
            acc = MFMA16(a_l, b_h, acc);
            acc = MFMA16(a_h, b_h, acc);
            c0[nt] = acc;
        }
        float s1[4] = {0,0,0,0}, s2[4] = {0,0,0,0};
        #pragma unroll
        for (int nt = 0; nt < 8; nt++){
            float bv = pb0[nt*16 + l16];
            #pragma unroll
            for (int rg = 0; rg < 4; rg++){
                float v = c0[nt][rg] + bv;
                c0[nt][rg] = v; s1[rg] += v; s2[rg] += v*v;
            }
        }
        #pragma unroll
        for (int m = 1; m < 16; m <<= 1)
            #pragma unroll
            for (int rg = 0; rg < 4; rg++){
                s1[rg] += __shfl_xor(s1[rg], m, 64);
                s2[rg] += __shfl_xor(s2[rg], m, 64);
            }
        #pragma unroll
        for (int rg = 0; rg < 4; rg++){
            float mean = s1[rg] * 0.0078125f;
            float var  = s2[rg] * 0.0078125f - mean*mean;
            s1[rg] = mean; s2[rg] = rsqrtf(var + 1e-6f);
        }
        #pragma unroll
        for (int nt = 0; nt < 8; nt++){
            float gv = pg0[nt*16 + l16], bev = pbe0[nt*16 + l16];
            #pragma unroll
            for (int rg = 0; rg < 4; rg++){
                float hv = (c0[nt][rg] - s1[rg]) * s2[rg] * gv + bev;
                h1r[nt][rg] = fmaxf(hv, 0.f);
            }
        }
    }
    __syncthreads();   // xm region now free (stripe scratch)

    // wave-local transpose of h1 -> A-frag registers (2KB stripe, half-K passes)
    bf16x8 ah1[4], al1[4];
    {
        char* sb = smem + XM + w*2048;
        #pragma unroll
        for (int half = 0; half < 2; half++){
            #pragma unroll
            for (int nt = half*4; nt < half*4 + 4; nt++){
                int col = nt*16 + l16;
                int gg = (col >> 3) - half*8;
                #pragma unroll
                for (int rg = 0; rg < 4; rg++)
                    *(unsigned short*)(sb + (gg*16 + q*4+rg)*16 + (col&7)*2) = f2bf(h1r[nt][rg]);
            }
            #pragma unroll
            for (int kr = half*2; kr < half*2 + 2; kr++)
                ah1[kr] = *(const bf16x8*)(sb + (((kr*4+q) - half*8)*16 + l16)*16);
        }
        #pragma unroll
        for (int half = 0; half < 2; half++){
            #pragma unroll
            for (int nt = half*4; nt < half*4 + 4; nt++){
                int col = nt*16 + l16;
                int gg = (col >> 3) - half*8;
                #pragma unroll
                for (int rg = 0; rg < 4; rg++){
                    unsigned short hi = f2bf(h1r[nt][rg]);
                    *(unsigned short*)(sb + (gg*16 + q*4+rg)*16 + (col&7)*2) = f2bf(h1r[nt][rg] - bf2f(hi));
                }
            }
            #pragma unroll
            for (int kr = half*2; kr < half*2 + 2; kr++)
                al1[kr] = *(const bf16x8*)(sb + (((kr*4+q) - half*8)*16 + l16)*16);
        }
    }

    // ---------------- phase 2: GEMM1 (4 K-rounds, split bf16x3) ----------------
    f32x4 c1[8];
    #pragma unroll
    for (int nt = 0; nt < 8; nt++) c1[nt] = fzero;
    auto g1round = [&](int base, bf16x8 ah, bf16x8 al){
        #pragma unroll
        for (int nt = 0; nt < 8; nt++){
            int n = nt*16 + l16;
            bf16x8 bhv = *(const bf16x8*)(smem + base + (q*128 + n)*16);
            bf16x8 blv = *(const bf16x8*)(smem + base + 8192 + (q*128 + n)*16);
            c1[nt] = MFMA16(ah, blv, c1[nt]);
            c1[nt] = MFMA16(al, bhv, c1[nt]);
            c1[nt] = MFMA16(ah, bhv, c1[nt]);
        }
    };
    g1round(W1A, ah1[0], al1[0]);
    g1round(W1B, ah1[1], al1[1]);
    __syncthreads();
    stage16k(W1A, WS_W1 + 32768);          // kr2
    stage16k(W1B, WS_W1 + 49152);          // kr3
    __syncthreads();
    g1round(W1A, ah1[2], al1[2]);
    g1round(W1B, ah1[3], al1[3]);

    // LN1 + relu + residual -> h2 (into h1r)
    {
        float s1[4] = {0,0,0,0}, s2[4] = {0,0,0,0};
        #pragma unroll
        for (int nt = 0; nt < 8; nt++){
            float bv = pb1[nt*16 + l16];
            #pragma unroll
            for (int rg = 0; rg < 4; rg++){
                float v = c1[nt][rg] + bv;
                c1[nt][rg] = v; s1[rg] += v; s2[rg] += v*v;
            }
        }
        #pragma unroll
        for (int m = 1; m < 16; m <<= 1)
            #pragma unroll
            for (int rg = 0; rg < 4; rg++){
                s1[rg] += __shfl_xor(s1[rg], m, 64);
                s2[rg] += __shfl_xor(s2[rg], m, 64);
            }
        #pragma unroll
        for (int rg = 0; rg < 4; rg++){
            float mean = s1[rg] * 0.0078125f;
            float var  = s2[rg] * 0.0078125f - mean*mean;
            s1[rg] = mean; s2[rg] = rsqrtf(var + 1e-6f);
        }
        #pragma unroll
        for (int nt = 0; nt < 8; nt++){
            float gv = pg1[nt*16 + l16], bev = pbe1[nt*16 + l16];
            #pragma unroll
            for (int rg = 0; rg < 4; rg++){
                float hv = (c1[nt][rg] - s1[rg]) * s2[rg] * gv + bev;
                h1r[nt][rg] = fmaxf(hv, 0.f) + h1r[nt][rg];
            }
        }
    }
    __syncthreads();   // all waves done reading W1A/W1B

    // ---------------- h2 -> block-wide transposed planes (hi @W1A, lo @W1B) ----------------
    #pragma unroll
    for (int nt = 0; nt < 8; nt++){
        int k = nt*16 + l16;
        #pragma unroll
        for (int rg = 0; rg < 4; rg++){
            int row = 16*w + q*4 + rg;
            float val = h1r[nt][rg];
            unsigned short hi = f2bf(val);
            int addr = row*256 + ((((k>>3) ^ (row&15)) & 15)*16) + (k&7)*2;
            *(unsigned short*)(smem + W1A + addr) = hi;
            *(unsigned short*)(smem + W1B + addr) = f2bf(val - bf2f(hi));
        }
    }
    __syncthreads();

    // ---------------- phase 3: wave-independent, 8 dims/wave, no barriers ----------------
    const char* wpl = ws + WS_WP + lane*16;
    const float* bpf = (const float*)(ws + WS_BP);
    float* xuLf = (float*)(smem + XU);
    float* yuLf = (float*)(smem + XM);
    const uint4 zero4 = {0,0,0,0};
    const bool pok = (lane & 31) < 25;
    const int hh = lane >> 5;
    const int d0 = w*8;
    const int rA = (lane & 31)*256, rB = (32 + (lane & 31))*256;
    auto rdB = [&](int pl, int rbase, int oct){
        return *(const bf16x8*)(smem + pl + rbase + (((oct ^ l16) & 15)*16));
    };
    uint4 A0[8], A1[8];
    #pragma unroll
    for (int kk = 0; kk < 8; kk++){ A0[kk] = zero4; A1[kk] = zero4; }
    if (pok){
        #pragma unroll
        for (int kk = 0; kk < 4; kk++){
            A0[kk]   = *(const uint4*)(wpl + d0*16384 + kk*1024);
            A0[4+kk] = *(const uint4*)(wpl + d0*16384 + 8192 + kk*1024);
        }
    }
    float ld_acc = 0.f;
    for (int i = 0; i < 8; i++){
        int c = d0 + i;
        if (pok){
            #pragma unroll
            for (int kk = 0; kk < 4; kk++){
                A1[kk]   = *(const uint4*)(wpl + c*16384 + (4+kk)*1024);
                A1[4+kk] = *(const uint4*)(wpl + c*16384 + 8192 + (4+kk)*1024);
            }
        }
        f32x16 t0, t1;
        #pragma unroll
        for (int z = 0; z < 16; z++){ t0[z] = 0.f; t1[z] = 0.f; }
        #pragma unroll
        for (int kk = 0; kk < 4; kk++){
            int oct = kk*2 + hh;
            bf16x8 ahh = *(bf16x8*)&A0[kk];
            bf16x8 all = *(bf16x8*)&A0[4+kk];
            bf16x8 b0h = rdB(W1A, rA, oct), b0l = rdB(W1B, rA, oct);
            bf16x8 b1h = rdB(W1A, rB, oct), b1l = rdB(W1B, rB, oct);
            t0 = MFMA32(ahh, b0l, t0); t1 = MFMA32(ahh, b1l, t1);
            t0 = MFMA32(all, b0h, t0); t1 = MFMA32(all, b1h, t1);
            t0 = MFMA32(ahh, b0h, t0); t1 = MFMA32(ahh, b1h, t1);
        }
        if (i < 7 && pok){
            #pragma unroll
            for (int kk = 0; kk < 4; kk++){
                A0[kk]   = *(const uint4*)(wpl + (c+1)*16384 + kk*1024);
                A0[4+kk] = *(const uint4*)(wpl + (c+1)*16384 + 8192 + kk*1024);
            }
        }
        #pragma unroll
        for (int kk = 0; kk < 4; kk++){
            int oct = (4+kk)*2 + hh;
            bf16x8 ahh = *(bf16x8*)&A1[kk];
            bf16x8 all = *(bf16x8*)&A1[4+kk];
            bf16x8 b0h = rdB(W1A, rA, oct), b0l = rdB(W1B, rA, oct);
            bf16x8 b1h = rdB(W1A, rB, oct), b1l = rdB(W1B, rB, oct);
            t0 = MFMA32(ahh, b0l, t0); t1 = MFMA32(ahh, b1l, t1);
            t0 = MFMA32(all, b0h, t0); t1 = MFMA32(all, b1h, t1);
            t0 = MFMA32(ahh, b0h, t0); t1 = MFMA32(ahh, b1h, t1);
        }
        // ---- pairwise spline: lanes (L, L^32) jointly handle rows L&31 (tile0) and 32+(L&31) (tile1)
        float xu0 = xuLf[c*64 + (lane & 31)];
        float xu1 = xuLf[c*64 + 32 + (lane & 31)];
        float xc0 = fminf(fmaxf(xu0, -3.f), 3.f);
        float xc1 = fminf(fmaxf(xu1, -3.f), 3.f);
        float4 bq0 = *(const float4*)(bpf + c*32 + 0  + 4*hh);
        float4 bq1 = *(const float4*)(bpf + c*32 + 8  + 4*hh);
        float4 bq2 = *(const float4*)(bpf + c*32 + 16 + 4*hh);
        float  bq3 = bpf[c*32 + 24 + 4*hh];
        float wv0[4], wv1[4], hv0[4], hv1[4], dv0[4], dv1[4];
        #pragma unroll
        for (int jj = 0; jj < 4; jj++){
            wv0[jj] = t0[jj] + bq0[jj];  hv0[jj] = t0[4+jj] + bq1[jj];  dv0[jj] = t0[8+jj] + bq2[jj];
            wv1[jj] = t1[jj] + bq0[jj];  hv1[jj] = t1[4+jj] + bq1[jj];  dv1[jj] = t1[8+jj] + bq2[jj];
        }
        float dx0 = t0[12] + bq3, dx1 = t1[12] + bq3;
        float bd0 = __shfl_xor(hh ? dv0[0] : dx0, 32, 64);
        float bd1 = __shfl_xor(hh ? dv1[0] : dx1, 32, 64);
        auto softscale = [&](float* a){
            float m = fmaxf(fmaxf(a[0],a[1]), fmaxf(a[2],a[3]));
            m = fmaxf(m, __shfl_xor(m, 32, 64));
            float e0 = __expf(a[0]-m), e1 = __expf(a[1]-m), e2 = __expf(a[2]-m), e3 = __expf(a[3]-m);
            float s = (e0+e1)+(e2+e3);
            s += __shfl_xor(s, 32, 64);
            float sc = 5.952f / s;
            a[0] = fmaf(e0, sc, 0.006f); a[1] = fmaf(e1, sc, 0.006f);
            a[2] = fmaf(e2, sc, 0.006f); a[3] = fmaf(e3, sc, 0.006f);
        };
        softscale(wv0); softscale(hv0); softscale(wv1); softscale(hv1);
        auto candf = [&](float* wv, float* hv, float* dv, float bdr, float xc,
                         float& X, float& Y, float& W, float& H, float& DK, float& DK1, float& V){
            float pw0 = wv[0], pw1 = pw0+wv[1], pw2 = pw1+wv[2], pw3 = pw2+wv[3];
            float ph0 = hv[0], ph1 = ph0+hv[1], ph2 = ph1+hv[2], ph3 = ph2+hv[3];
            float offw = __shfl_xor(pw3, 32, 64);
            float offh = __shfl_xor(ph3, 32, 64);
            float bw = hh ? (offw - 3.f) : -3.f;
            float by = hh ? (offh - 3.f) : -3.f;
            X = bw; Y = by; W = wv[0]; H = hv[0]; DK = dv[0]; DK1 = dv[1];
            float e1_ = bw + pw0, e2_ = bw + pw1, e3_ = bw + pw2;
            if (xc >= e1_){ X = e1_; Y = by + ph0; W = wv[1]; H = hv[1]; DK = dv[1]; DK1 = dv[2]; }
            if (xc >= e2_){ X = e2_; Y = by + ph1; W = wv[2]; H = hv[2]; DK = dv[2]; DK1 = dv[3]; }
            if (xc >= e3_){ X = e3_; Y = by + ph2; W = wv[3]; H = hv[3]; DK = dv[3]; DK1 = bdr;  }
            V = (!hh || xc >= bw) ? 1.f : 0.f;
        };
        float X0,Y0,Wc0,Hc0,K0,K10,V0, X1,Y1,Wc1,Hc1,K1,K11,V1;
        candf(wv0, hv0, dv0, bd0, xc0, X0,Y0,Wc0,Hc0,K0,K10,V0);
        candf(wv1, hv1, dv1, bd1, xc1, X1,Y1,Wc1,Hc1,K1,K11,V1);
        float rX  = __shfl_xor(hh ? X0  : X1 , 32, 64);
        float rY  = __shfl_xor(hh ? Y0  : Y1 , 32, 64);
        float rW  = __shfl_xor(hh ? Wc0 : Wc1, 32, 64);
        float rH  = __shfl_xor(hh ? Hc0 : Hc1, 32, 64);
        float rK  = __shfl_xor(hh ? K0  : K1 , 32, 64);
        float rK1 = __shfl_xor(hh ? K10 : K11, 32, 64);
        float rV  = __shfl_xor(hh ? V0  : V1 , 32, 64);
        float oX  = hh ? X1  : X0,  oY  = hh ? Y1  : Y0,  oW = hh ? Wc1 : Wc0;
        float oH  = hh ? Hc1 : Hc0, oK  = hh ? K1  : K0,  oK1 = hh ? K11 : K10;
        float oV  = hh ? V1  : V0;
        bool useh1 = ((hh ? oV : rV) > 0.5f);
        bool useOwn = (hh != 0) == useh1;
        float X = useOwn ? oX : rX,  Y = useOwn ? oY : rY;
        float W = useOwn ? oW : rW,  H = useOwn ? oH : rH;
        float K = useOwn ? oK : rK,  K1s = useOwn ? oK1 : rK1;
        float xu = hh ? xu1 : xu0;
        float xc = hh ? xc1 : xc0;
        float DKs  = fmaxf(K, 0.f)   + __logf(1.f + __expf(-fabsf(K)))   + 0.001f;
        float DK1s = fmaxf(K1s, 0.f) + __logf(1.f + __expf(-fabsf(K1s))) + 0.001f;
        float iw = 1.f / W;
        float s_ = H * iw;
        float th = (xc - X) * iw;
        float om = 1.f - th;
        float t1m = th * om;
        float den = s_ + (DK1s + DKs - 2.f*s_) * t1m;
        float yin = Y + H * (s_*th*th + DKs*t1m) / den;
        float num2 = DK1s*th*th + 2.f*s_*t1m + DKs*om*om;
        float ldin = 2.f*__logf(s_) + __logf(num2) - 2.f*__logf(den);
        bool inside = (xu > -3.f) && (xu < 3.f);
        yuLf[c*64 + lane] = inside ? yin : xu;   // lane L finalizes global row L
        ld_acc += inside ? ldin : 0.f;
    }

    // ---------------- epilogue ----------------
    __syncthreads();                       // xu dead; yu complete
    *(float*)(smem + XU + (w*64 + lane)*4) = ld_acc;
    __syncthreads();
    if (t < 64){
        const float* lp = (const float*)(smem + XU);
        ldout[r0 + t] = (lp[t] + lp[64 + t]) + (lp[128 + t] + lp[192 + t]);
    }
    {
        int row = t >> 2, part = t & 3;
        const float* xrow = x + (size_t)(r0 + row)*64;
        float* yrow = yout + (size_t)(r0 + row)*64;
        const float* yuL = (const float*)(smem + XM);
        #pragma unroll
        for (int j = 0; j < 4; j++){
            int s = part*4 + j;
            float4 xv = ((const float4*)xrow)[s];
            float4 o;
            o.x = xv.x; o.z = xv.z;
            o.y = yuL[(2*s)*64 + row];
            o.w = yuL[(2*s+1)*64 + row];
            ((float4*)yrow)[s] = o;
        }
    }
}

extern "C" void kernel_launch(void* const* d_in, const int* in_sizes, int n_in,
                              void* d_out, int out_size, void* d_ws, size_t ws_size,
                              hipStream_t stream)
{
    const float* x   = (const float*)d_in[0];
    const float* W0  = (const float*)d_in[1];
    const float* b0  = (const float*)d_in[2];
    const float* g0  = (const float*)d_in[3];
    const float* be0 = (const float*)d_in[4];
    const float* W1  = (const float*)d_in[5];
    const float* b1  = (const float*)d_in[6];
    const float* g1  = (const float*)d_in[7];
    const float* be1 = (const float*)d_in[8];
    const float* Wp  = (const float*)d_in[9];
    const float* bp  = (const float*)d_in[10];
    float* y = (float*)d_out;
    float* ldo = y + (size_t)NROWS * 64;
    char* ws = (char*)d_ws;

    hipLaunchKernelGGL(prep_kernel, dim3(152), dim3(256), 0, stream, W0, W1, Wp, bp, ws);
    hipLaunchKernelGGL(main_kernel, dim3(4096), dim3(256), 0, stream,
                       x, b0, g0, be0, b1, g1, be1, ws, y, ldo);
}